// Round 1
// baseline (1550.041 us; speedup 1.0000x reference)
//
#include <hip/hip_runtime.h>

typedef unsigned short u16;
typedef __bf16 bf16x8 __attribute__((ext_vector_type(8)));
typedef float f32x4 __attribute__((ext_vector_type(4)));
typedef short s16x8 __attribute__((ext_vector_type(8)));
typedef float f32x4v __attribute__((ext_vector_type(4)));

__device__ __forceinline__ float bf2f(u16 u) {
    unsigned x = ((unsigned)u) << 16;
    return __builtin_bit_cast(float, x);
}
__device__ __forceinline__ u16 f2bf(float f) {
    unsigned x = __builtin_bit_cast(unsigned, f);
    unsigned r = (x + 0x7FFFu + ((x >> 16) & 1u)) >> 16;
    return (u16)r;
}

// ---------------- f32 -> bf16 conversion ----------------
__global__ __launch_bounds__(256) void cvt_kernel(const float* __restrict__ in,
                                                  u16* __restrict__ out, long n) {
    typedef u16 u16x4 __attribute__((ext_vector_type(4)));
    for (long i = (long)blockIdx.x * 1024 + (long)threadIdx.x * 4; i < n;
         i += (long)gridDim.x * 1024) {
        f32x4v v = *(const f32x4v*)(in + i);
        u16x4 o;
        o.x = f2bf(v.x); o.y = f2bf(v.y); o.z = f2bf(v.z); o.w = f2bf(v.w);
        *(u16x4*)(out + i) = o;
    }
}

// ---------------- embedding ----------------
__global__ __launch_bounds__(256) void embed_kernel(const int* __restrict__ x,
                                                    const float* __restrict__ tok,
                                                    const float* __restrict__ pos,
                                                    float* __restrict__ h) {
    int row = blockIdx.x;           // [0, 2048)
    int t = row & 1023;
    long id = x[row];
    const float* te = tok + id * 768L;
    const float* pe = pos + (long)t * 768L;
    float* o = h + (long)row * 768L;
    for (int d = threadIdx.x; d < 768; d += 256) o[d] = te[d] + pe[d];
}

// ---------------- layernorm (f32 in, bf16 out) ----------------
__global__ __launch_bounds__(256) void ln_kernel(const float* __restrict__ x,
                                                 const float* __restrict__ w,
                                                 const float* __restrict__ b,
                                                 u16* __restrict__ out) {
    __shared__ float red[4];
    int row = blockIdx.x;
    const float* xr = x + (long)row * 768L;
    int tid = threadIdx.x, lane = tid & 63, wid = tid >> 6;
    float v0 = xr[tid], v1 = xr[tid + 256], v2 = xr[tid + 512];
    float s = v0 + v1 + v2;
    for (int o = 32; o; o >>= 1) s += __shfl_xor(s, o);
    if (lane == 0) red[wid] = s;
    __syncthreads();
    float mean = (red[0] + red[1] + red[2] + red[3]) * (1.f / 768.f);
    __syncthreads();
    float d0 = v0 - mean, d1 = v1 - mean, d2 = v2 - mean;
    float q = d0 * d0 + d1 * d1 + d2 * d2;
    for (int o = 32; o; o >>= 1) q += __shfl_xor(q, o);
    if (lane == 0) red[wid] = q;
    __syncthreads();
    float var = (red[0] + red[1] + red[2] + red[3]) * (1.f / 768.f);
    float rstd = rsqrtf(var + 1e-5f);
    u16* orow = out + (long)row * 768L;
    orow[tid]       = f2bf(d0 * rstd * w[tid]       + b[tid]);
    orow[tid + 256] = f2bf(d1 * rstd * w[tid + 256] + b[tid + 256]);
    orow[tid + 512] = f2bf(d2 * rstd * w[tid + 512] + b[tid + 512]);
}

// ---------------- softmax over score rows (in-place, bf16) ----------------
__global__ __launch_bounds__(256) void softmax_kernel(u16* __restrict__ scores) {
    __shared__ float red[4];
    int t = blockIdx.x, z = blockIdx.y;
    u16* row = scores + ((long)z * 1024 + t) * 1024L;
    int tid = threadIdx.x, lane = tid & 63, wid = tid >> 6;
    float v[4];
    float mx = -1e30f;
#pragma unroll
    for (int j = 0; j < 4; j++) {
        int s = tid + 256 * j;
        v[j] = (s <= t) ? bf2f(row[s]) : -1e30f;
        mx = fmaxf(mx, v[j]);
    }
    for (int o = 32; o; o >>= 1) mx = fmaxf(mx, __shfl_xor(mx, o));
    if (lane == 0) red[wid] = mx;
    __syncthreads();
    mx = fmaxf(fmaxf(red[0], red[1]), fmaxf(red[2], red[3]));
    __syncthreads();
    float e[4], ssum = 0.f;
#pragma unroll
    for (int j = 0; j < 4; j++) {
        int s = tid + 256 * j;
        e[j] = (s <= t) ? __expf(v[j] - mx) : 0.f;
        ssum += e[j];
    }
    for (int o = 32; o; o >>= 1) ssum += __shfl_xor(ssum, o);
    if (lane == 0) red[wid] = ssum;
    __syncthreads();
    ssum = red[0] + red[1] + red[2] + red[3];
    float inv = 1.f / ssum;
#pragma unroll
    for (int j = 0; j < 4; j++) row[tid + 256 * j] = f2bf(e[j] * inv);
}

// ---------------- MFMA GEMM:  C = A @ B^T (+epilogue) ----------------
// A: [M,K] bf16 (lda), B: trans ? [N,K] : [K,N] bf16, C per EPI.
// batched via blockIdx.z: zb=z/H, zh=z%H; off = zb*sb + zh*sh per matrix.
// EPI: 0 = write bf16; 1 = +bias -> bf16; 2 = relu(+bias) -> bf16;
//      3 = C += acc + bias (f32, in-place residual); 4 = *scale -> bf16;
//      5 = write f32.
template <int BM, int BN, int EPI, bool BTRANS, bool CSKIP>
__global__ __launch_bounds__(256) void gemm_kernel(
    const u16* __restrict__ A, int lda, long sAb, long sAh,
    const u16* __restrict__ Bm, int ldb, long sBb, long sBh,
    void* __restrict__ Cv, int ldc, long sCb, long sCh,
    const float* __restrict__ bias, int K, int Hh, float scale) {
    constexpr int BK = 32;
    int bn0 = blockIdx.x * BN, bm0 = blockIdx.y * BM;
    if (CSKIP && bn0 > bm0 + BM - 1) return;  // fully-masked causal tile
    int z = blockIdx.z;
    int zb = z / Hh, zh = z % Hh;
    const u16* Ab = A + zb * sAb + zh * sAh + (long)bm0 * lda;
    const u16* Bb = Bm + zb * sBb + zh * sBh;
    if (BTRANS) Bb += (long)bn0 * ldb; else Bb += bn0;

    __shared__ u16 As[BM * BK];
    __shared__ u16 Bs[BN * BK];

    int tid = threadIdx.x, lane = tid & 63, wid = tid >> 6;
    constexpr int WM = BM / 2, WN = BN / 2, MR = WM / 16, NR = WN / 16;
    int wm0 = (wid >> 1) * WM, wn0 = (wid & 1) * WN;

    f32x4 acc[MR][NR];
#pragma unroll
    for (int mi = 0; mi < MR; mi++)
#pragma unroll
        for (int ni = 0; ni < NR; ni++) acc[mi][ni] = 0.f;

    for (int k0 = 0; k0 < K; k0 += BK) {
        // stage A tile [BM][BK] via direct global->LDS (16B/lane)
        constexpr int CA = BM * BK / 8;
#pragma unroll
        for (int c = tid; c < CA; c += 256) {
            const u16* src = Ab + (long)(c >> 2) * lda + k0 + (c & 3) * 8;
            __builtin_amdgcn_global_load_lds(
                (const __attribute__((address_space(1))) unsigned*)src,
                (__attribute__((address_space(3))) unsigned*)(As + c * 8), 16, 0, 0);
        }
        if (BTRANS) {
            constexpr int CB = BN * BK / 8;
#pragma unroll
            for (int c = tid; c < CB; c += 256) {
                const u16* src = Bb + (long)(c >> 2) * ldb + k0 + (c & 3) * 8;
                __builtin_amdgcn_global_load_lds(
                    (const __attribute__((address_space(1))) unsigned*)src,
                    (__attribute__((address_space(3))) unsigned*)(Bs + c * 8), 16, 0, 0);
            }
        } else {
            // B is [K,N]: transpose into Bs[n][k]
            constexpr int CGB = BN / 8;
#pragma unroll
            for (int c = tid; c < BK * CGB; c += 256) {
                int kk = c / CGB, n0 = (c % CGB) * 8;
                s16x8 vv = *(const s16x8*)(Bb + (long)(k0 + kk) * ldb + n0);
#pragma unroll
                for (int j = 0; j < 8; j++)
                    Bs[(n0 + j) * BK + kk] = ((const u16*)&vv)[j];
            }
        }
        __syncthreads();
        bf16x8 af[MR], bfr[NR];
#pragma unroll
        for (int mi = 0; mi < MR; mi++)
            af[mi] = *(const bf16x8*)(As + (wm0 + mi * 16 + (lane & 15)) * BK + 8 * (lane >> 4));
#pragma unroll
        for (int ni = 0; ni < NR; ni++)
            bfr[ni] = *(const bf16x8*)(Bs + (wn0 + ni * 16 + (lane & 15)) * BK + 8 * (lane >> 4));
#pragma unroll
        for (int mi = 0; mi < MR; mi++)
#pragma unroll
            for (int ni = 0; ni < NR; ni++)
                acc[mi][ni] = __builtin_amdgcn_mfma_f32_16x16x32_bf16(
                    af[mi], bfr[ni], acc[mi][ni], 0, 0, 0);
        __syncthreads();
    }

    long coff = zb * sCb + zh * sCh;
#pragma unroll
    for (int mi = 0; mi < MR; mi++)
#pragma unroll
        for (int ni = 0; ni < NR; ni++)
#pragma unroll
            for (int j = 0; j < 4; j++) {
                int gm = bm0 + wm0 + mi * 16 + ((lane >> 4) << 2) + j;
                int gn = bn0 + wn0 + ni * 16 + (lane & 15);
                float v = acc[mi][ni][j];
                long idx = coff + (long)gm * ldc + gn;
                if (EPI == 0) ((u16*)Cv)[idx] = f2bf(v);
                else if (EPI == 1) ((u16*)Cv)[idx] = f2bf(v + bias[gn]);
                else if (EPI == 2) ((u16*)Cv)[idx] = f2bf(fmaxf(v + bias[gn], 0.f));
                else if (EPI == 3) { float* C = (float*)Cv; C[idx] = C[idx] + v + bias[gn]; }
                else if (EPI == 4) ((u16*)Cv)[idx] = f2bf(v * scale);
                else ((float*)Cv)[idx] = v;
            }
}

// ---------------- host side ----------------
extern "C" void kernel_launch(void* const* d_in, const int* in_sizes, int n_in,
                              void* d_out, int out_size, void* d_ws, size_t ws_size,
                              hipStream_t stream) {
    const int L = 6, D = 768, Hn = 12, F = 3072, T = 1024, V = 32000;
    const int M = 2048;  // B*T
    const int* x = (const int*)d_in[0];
    const float* tok = (const float*)d_in[1];
    const float* pos = (const float*)d_in[2];
    const float* ln1w = (const float*)d_in[3];
    const float* ln1b = (const float*)d_in[4];
    const float* wq = (const float*)d_in[5];
    const float* bq = (const float*)d_in[6];
    const float* wk = (const float*)d_in[7];
    const float* bk = (const float*)d_in[8];
    const float* wv = (const float*)d_in[9];
    const float* bv = (const float*)d_in[10];
    const float* wo = (const float*)d_in[11];
    const float* bo = (const float*)d_in[12];
    const float* ln2w = (const float*)d_in[13];
    const float* ln2b = (const float*)d_in[14];
    const float* w1 = (const float*)d_in[15];
    const float* b1 = (const float*)d_in[16];
    const float* w2 = (const float*)d_in[17];
    const float* b2 = (const float*)d_in[18];
    const float* lnfw = (const float*)d_in[19];
    const float* lnfb = (const float*)d_in[20];
    const float* headw = (const float*)d_in[21];

    char* p = (char*)d_ws;
    auto alloc = [&](size_t bytes) {
        char* r = p;
        p += (bytes + 255) & ~(size_t)255;
        return r;
    };
    const long DD = (long)D * D, FD = (long)F * D;
    u16* wq_b = (u16*)alloc(L * DD * 2);
    u16* wk_b = (u16*)alloc(L * DD * 2);
    u16* wv_b = (u16*)alloc(L * DD * 2);
    u16* wo_b = (u16*)alloc(L * DD * 2);
    u16* w1_b = (u16*)alloc(L * FD * 2);
    u16* w2_b = (u16*)alloc(L * FD * 2);
    u16* hw_b = (u16*)alloc((long)V * D * 2);
    float* h = (float*)alloc((long)M * D * 4);
    u16* a = (u16*)alloc((long)M * D * 2);
    u16* qb = (u16*)alloc((long)M * D * 2);
    u16* kb = (u16*)alloc((long)M * D * 2);
    u16* vb = (u16*)alloc((long)M * D * 2);
    u16* ctxb = (u16*)alloc((long)M * D * 2);
    u16* f1 = (u16*)alloc((long)M * F * 2);
    u16* sc = (u16*)alloc(24L * T * T * 2);

    auto cvt = [&](const float* src, u16* dst, long n) {
        long blocks = (n + 1023) / 1024;
        if (blocks > 8192) blocks = 8192;
        cvt_kernel<<<dim3((unsigned)blocks), 256, 0, stream>>>(src, dst, n);
    };
    cvt(wq, wq_b, L * DD);
    cvt(wk, wk_b, L * DD);
    cvt(wv, wv_b, L * DD);
    cvt(wo, wo_b, L * DD);
    cvt(w1, w1_b, L * FD);
    cvt(w2, w2_b, L * FD);
    cvt(headw, hw_b, (long)V * D);

    embed_kernel<<<dim3(M), 256, 0, stream>>>(x, tok, pos, h);

    const long sTD = (long)T * D;   // per-batch stride in q/k/v/ctx
    const long sTT = (long)T * T;   // per-head stride in scores
    for (int i = 0; i < L; i++) {
        ln_kernel<<<dim3(M), 256, 0, stream>>>(h, ln1w + i * D, ln1b + i * D, a);
        dim3 gqkv(D / 64, M / 64, 1);
        gemm_kernel<64, 64, 1, true, false><<<gqkv, 256, 0, stream>>>(
            a, D, 0, 0, wq_b + i * DD, D, 0, 0, qb, D, 0, 0, bq + i * D, D, 1, 0.f);
        gemm_kernel<64, 64, 1, true, false><<<gqkv, 256, 0, stream>>>(
            a, D, 0, 0, wk_b + i * DD, D, 0, 0, kb, D, 0, 0, bk + i * D, D, 1, 0.f);
        gemm_kernel<64, 64, 1, true, false><<<gqkv, 256, 0, stream>>>(
            a, D, 0, 0, wv_b + i * DD, D, 0, 0, vb, D, 0, 0, bv + i * D, D, 1, 0.f);
        // scores = scale * Q@K^T   [24 batches of T x T], K=64
        dim3 gs(T / 64, T / 64, 24);
        gemm_kernel<64, 64, 4, true, true><<<gs, 256, 0, stream>>>(
            qb, D, sTD, 64, kb, D, sTD, 64, sc, T, (long)Hn * sTT, sTT,
            nullptr, 64, Hn, 0.125f);
        softmax_kernel<<<dim3(T, 24), 256, 0, stream>>>(sc);
        // ctx = P@V   [24 batches of T x 64], K=T, B is [K,N] (needs transpose stage)
        dim3 gp(1, T / 64, 24);
        gemm_kernel<64, 64, 0, false, false><<<gp, 256, 0, stream>>>(
            sc, T, (long)Hn * sTT, sTT, vb, D, sTD, 64, ctxb, D, sTD, 64,
            nullptr, T, Hn, 0.f);
        // h += ctx @ wo^T + bo
        gemm_kernel<64, 64, 3, true, false><<<gqkv, 256, 0, stream>>>(
            ctxb, D, 0, 0, wo_b + i * DD, D, 0, 0, h, D, 0, 0, bo + i * D, D, 1, 0.f);
        ln_kernel<<<dim3(M), 256, 0, stream>>>(h, ln2w + i * D, ln2b + i * D, a);
        // f1 = relu(a @ w1^T + b1)
        dim3 gf1(F / 128, M / 128, 1);
        gemm_kernel<128, 128, 2, true, false><<<gf1, 256, 0, stream>>>(
            a, D, 0, 0, w1_b + i * FD, D, 0, 0, f1, F, 0, 0, b1 + i * F, D, 1, 0.f);
        // h += f1 @ w2^T + b2
        dim3 gf2(D / 64, M / 64, 1);
        gemm_kernel<64, 64, 3, true, false><<<gf2, 256, 0, stream>>>(
            f1, F, 0, 0, w2_b + i * FD, F, 0, 0, h, D, 0, 0, b2 + i * D, F, 1, 0.f);
    }
    ln_kernel<<<dim3(M), 256, 0, stream>>>(h, lnfw, lnfb, a);
    // logits = a @ head_w^T  -> f32 d_out
    dim3 gh(V / 128, M / 128, 1);
    gemm_kernel<128, 128, 5, true, false><<<gh, 256, 0, stream>>>(
        a, D, 0, 0, hw_b, D, 0, 0, d_out, V, 0, 0, nullptr, D, 1, 0.f);
}

// Round 2
// 1516.765 us; speedup vs baseline: 1.0219x; 1.0219x over previous
//
#include <hip/hip_runtime.h>

typedef unsigned short u16;
typedef __bf16 bf16x8 __attribute__((ext_vector_type(8)));
typedef float f32x4 __attribute__((ext_vector_type(4)));
typedef float f32x4v __attribute__((ext_vector_type(4)));
typedef u16 u16x4 __attribute__((ext_vector_type(4)));

__device__ __forceinline__ float bf2f(u16 u) {
    unsigned x = ((unsigned)u) << 16;
    return __builtin_bit_cast(float, x);
}
__device__ __forceinline__ u16 f2bf(float f) {
    unsigned x = __builtin_bit_cast(unsigned, f);
    unsigned r = (x + 0x7FFFu + ((x >> 16) & 1u)) >> 16;
    return (u16)r;
}

// ---------------- f32 -> bf16 conversion (chunk-strided dest) ----------------
// out[(i/chunk)*stride + i%chunk] = bf16(in[i])
__global__ __launch_bounds__(256) void cvt_kernel(const float* __restrict__ in,
                                                  u16* __restrict__ out, long n,
                                                  long chunk, long stride) {
    for (long i = (long)blockIdx.x * 1024 + (long)threadIdx.x * 4; i < n;
         i += (long)gridDim.x * 1024) {
        f32x4v v = *(const f32x4v*)(in + i);
        u16x4 o;
        o.x = f2bf(v.x); o.y = f2bf(v.y); o.z = f2bf(v.z); o.w = f2bf(v.w);
        long c = i / chunk, rrem = i - c * chunk;
        *(u16x4*)(out + c * stride + rrem) = o;
    }
}

// ---------------- fused qkv bias ----------------
__global__ __launch_bounds__(256) void bias_fuse_kernel(const float* __restrict__ bq,
                                                        const float* __restrict__ bk,
                                                        const float* __restrict__ bv,
                                                        float* __restrict__ dst) {
    int i = blockIdx.x * 256 + threadIdx.x;
    if (i < 6 * 768) {
        int l = i / 768, j = i % 768;
        dst[l * 2304 + j] = bq[i];
        dst[l * 2304 + 768 + j] = bk[i];
        dst[l * 2304 + 1536 + j] = bv[i];
    }
}

// ---------------- embedding ----------------
__global__ __launch_bounds__(256) void embed_kernel(const int* __restrict__ x,
                                                    const float* __restrict__ tok,
                                                    const float* __restrict__ pos,
                                                    float* __restrict__ h) {
    int row = blockIdx.x;           // [0, 2048)
    int t = row & 1023;
    long id = x[row];
    const float* te = tok + id * 768L;
    const float* pe = pos + (long)t * 768L;
    float* o = h + (long)row * 768L;
    for (int d = threadIdx.x; d < 768; d += 256) o[d] = te[d] + pe[d];
}

// ---------------- layernorm (f32 in, bf16 out) ----------------
__global__ __launch_bounds__(256) void ln_kernel(const float* __restrict__ x,
                                                 const float* __restrict__ w,
                                                 const float* __restrict__ b,
                                                 u16* __restrict__ out) {
    __shared__ float red[4];
    int row = blockIdx.x;
    const float* xr = x + (long)row * 768L;
    int tid = threadIdx.x, lane = tid & 63, wid = tid >> 6;
    float v0 = xr[tid], v1 = xr[tid + 256], v2 = xr[tid + 512];
    float s = v0 + v1 + v2;
    for (int o = 32; o; o >>= 1) s += __shfl_xor(s, o);
    if (lane == 0) red[wid] = s;
    __syncthreads();
    float mean = (red[0] + red[1] + red[2] + red[3]) * (1.f / 768.f);
    __syncthreads();
    float d0 = v0 - mean, d1 = v1 - mean, d2 = v2 - mean;
    float q = d0 * d0 + d1 * d1 + d2 * d2;
    for (int o = 32; o; o >>= 1) q += __shfl_xor(q, o);
    if (lane == 0) red[wid] = q;
    __syncthreads();
    float var = (red[0] + red[1] + red[2] + red[3]) * (1.f / 768.f);
    float rstd = rsqrtf(var + 1e-5f);
    u16* orow = out + (long)row * 768L;
    orow[tid]       = f2bf(d0 * rstd * w[tid]       + b[tid]);
    orow[tid + 256] = f2bf(d1 * rstd * w[tid + 256] + b[tid + 256]);
    orow[tid + 512] = f2bf(d2 * rstd * w[tid + 512] + b[tid + 512]);
}

// ---------------- softmax over score rows (in-place, bf16) ----------------
__global__ __launch_bounds__(256) void softmax_kernel(u16* __restrict__ scores) {
    __shared__ float red[4];
    int t = blockIdx.x, z = blockIdx.y;
    u16* row = scores + ((long)z * 1024 + t) * 1024L;
    int tid = threadIdx.x, lane = tid & 63, wid = tid >> 6;
    float v[4];
    float mx = -1e30f;
#pragma unroll
    for (int j = 0; j < 4; j++) {
        int s = tid + 256 * j;
        v[j] = (s <= t) ? bf2f(row[s]) : -1e30f;
        mx = fmaxf(mx, v[j]);
    }
    for (int o = 32; o; o >>= 1) mx = fmaxf(mx, __shfl_xor(mx, o));
    if (lane == 0) red[wid] = mx;
    __syncthreads();
    mx = fmaxf(fmaxf(red[0], red[1]), fmaxf(red[2], red[3]));
    __syncthreads();
    float e[4], ssum = 0.f;
#pragma unroll
    for (int j = 0; j < 4; j++) {
        int s = tid + 256 * j;
        e[j] = (s <= t) ? __expf(v[j] - mx) : 0.f;
        ssum += e[j];
    }
    for (int o = 32; o; o >>= 1) ssum += __shfl_xor(ssum, o);
    if (lane == 0) red[wid] = ssum;
    __syncthreads();
    ssum = red[0] + red[1] + red[2] + red[3];
    float inv = 1.f / ssum;
#pragma unroll
    for (int j = 0; j < 4; j++) row[tid + 256 * j] = f2bf(e[j] * inv);
}

// ---------------- MFMA GEMM v2:  C = A @ B^T (+epilogue) ----------------
// Flat 1D xy-grid (grid.x = gm*gn), M-major decomposition + bijective XCD
// swizzle (consecutive blocks on one XCD share the B-tile, walk M).
// A: [M,K] bf16 (lda); B: [N,K] bf16 (ldb); batch via blockIdx.z.
// EPI: 0 bf16; 1 +bias bf16; 2 relu(+bias) bf16; 3 C += acc+bias (f32);
//      4 *scale bf16; 5 f32; 6 qkv-split (q,k -> C, v -> aux transposed).
template <int BM, int BN, int EPI, bool CSKIP, bool KLIM>
__global__ __launch_bounds__(256) void gemm2_kernel(
    const u16* __restrict__ A, int lda, long sAb, long sAh,
    const u16* __restrict__ Bm, int ldb, long sBb, long sBh,
    void* __restrict__ Cv, int ldc, long sCb, long sCh,
    const float* __restrict__ bias, int K, int gm, int Hh, float scale,
    u16* __restrict__ aux) {
    constexpr int BK = 32;
    int nwg = gridDim.x, flat = blockIdx.x;
    int q = nwg >> 3, r = nwg & 7;
    int xcd = flat & 7, wi = flat >> 3;
    int swz = (xcd < r) ? (xcd * (q + 1) + wi) : (r * (q + 1) + (xcd - r) * q + wi);
    int nt = swz / gm, mt = swz - nt * gm;
    int bm0 = mt * BM, bn0 = nt * BN;
    if (CSKIP && bn0 > bm0 + BM - 1) return;  // fully-masked causal tile
    int z = blockIdx.z;
    int zb = z / Hh, zh = z - zb * Hh;
    const u16* Ab = A + zb * sAb + zh * sAh + (long)bm0 * lda;
    const u16* Bb = Bm + zb * sBb + zh * sBh + (long)bn0 * ldb;

    __shared__ u16 As[BM * BK];
    __shared__ u16 Bs[BN * BK];

    int tid = threadIdx.x, lane = tid & 63, wid = tid >> 6;
    constexpr int WM = BM / 2, WN = BN / 2, MR = WM / 16, NR = WN / 16;
    int wm0 = (wid >> 1) * WM, wn0 = (wid & 1) * WN;

    f32x4 acc[MR][NR];
#pragma unroll
    for (int mi = 0; mi < MR; mi++)
#pragma unroll
        for (int ni = 0; ni < NR; ni++) acc[mi][ni] = 0.f;

    int Keff = KLIM ? (bm0 + BM < K ? bm0 + BM : K) : K;
    for (int k0 = 0; k0 < Keff; k0 += BK) {
        constexpr int CA = BM * BK / 8;
#pragma unroll
        for (int c = tid; c < CA; c += 256) {
            const u16* src = Ab + (long)(c >> 2) * lda + k0 + (c & 3) * 8;
            __builtin_amdgcn_global_load_lds(
                (const __attribute__((address_space(1))) unsigned*)src,
                (__attribute__((address_space(3))) unsigned*)(As + c * 8), 16, 0, 0);
        }
        constexpr int CB = BN * BK / 8;
#pragma unroll
        for (int c = tid; c < CB; c += 256) {
            const u16* src = Bb + (long)(c >> 2) * ldb + k0 + (c & 3) * 8;
            __builtin_amdgcn_global_load_lds(
                (const __attribute__((address_space(1))) unsigned*)src,
                (__attribute__((address_space(3))) unsigned*)(Bs + c * 8), 16, 0, 0);
        }
        __syncthreads();
        bf16x8 af[MR], bfr[NR];
#pragma unroll
        for (int mi = 0; mi < MR; mi++)
            af[mi] = *(const bf16x8*)(As + (wm0 + mi * 16 + (lane & 15)) * BK + 8 * (lane >> 4));
#pragma unroll
        for (int ni = 0; ni < NR; ni++)
            bfr[ni] = *(const bf16x8*)(Bs + (wn0 + ni * 16 + (lane & 15)) * BK + 8 * (lane >> 4));
#pragma unroll
        for (int mi = 0; mi < MR; mi++)
#pragma unroll
            for (int ni = 0; ni < NR; ni++)
                acc[mi][ni] = __builtin_amdgcn_mfma_f32_16x16x32_bf16(
                    af[mi], bfr[ni], acc[mi][ni], 0, 0, 0);
        __syncthreads();
    }

    long coff = zb * sCb + zh * sCh;
#pragma unroll
    for (int mi = 0; mi < MR; mi++)
#pragma unroll
        for (int ni = 0; ni < NR; ni++) {
            int gmb = bm0 + wm0 + mi * 16 + ((lane >> 4) << 2);
            int gn = bn0 + wn0 + ni * 16 + (lane & 15);
            if (EPI == 6) {
                if (gn < 1536) {
#pragma unroll
                    for (int j = 0; j < 4; j++)
                        ((u16*)Cv)[(long)(gmb + j) * ldc + gn] =
                            f2bf(acc[mi][ni][j] + bias[gn]);
                } else {
                    u16x4 o;
#pragma unroll
                    for (int j = 0; j < 4; j++) o[j] = f2bf(acc[mi][ni][j] + bias[gn]);
                    int hh = (gn - 1536) >> 6, dk = gn & 63;
                    long off = ((long)((gmb >> 10) * 12 + hh) * 64 + dk) * 1024 + (gmb & 1023);
                    *(u16x4*)(aux + off) = o;
                }
            } else {
#pragma unroll
                for (int j = 0; j < 4; j++) {
                    float v = acc[mi][ni][j];
                    long idx = coff + (long)(gmb + j) * ldc + gn;
                    if (EPI == 0) ((u16*)Cv)[idx] = f2bf(v);
                    else if (EPI == 1) ((u16*)Cv)[idx] = f2bf(v + bias[gn]);
                    else if (EPI == 2) ((u16*)Cv)[idx] = f2bf(fmaxf(v + bias[gn], 0.f));
                    else if (EPI == 3) { float* C = (float*)Cv; C[idx] = C[idx] + v + bias[gn]; }
                    else if (EPI == 4) ((u16*)Cv)[idx] = f2bf(v * scale);
                    else ((float*)Cv)[idx] = v;
                }
            }
        }
}

// ---------------- host side ----------------
extern "C" void kernel_launch(void* const* d_in, const int* in_sizes, int n_in,
                              void* d_out, int out_size, void* d_ws, size_t ws_size,
                              hipStream_t stream) {
    const int L = 6, D = 768, Hn = 12, F = 3072, T = 1024, V = 32000;
    const int M = 2048;  // B*T
    const int* x = (const int*)d_in[0];
    const float* tok = (const float*)d_in[1];
    const float* pos = (const float*)d_in[2];
    const float* ln1w = (const float*)d_in[3];
    const float* ln1b = (const float*)d_in[4];
    const float* wq = (const float*)d_in[5];
    const float* bq = (const float*)d_in[6];
    const float* wk = (const float*)d_in[7];
    const float* bk = (const float*)d_in[8];
    const float* wv = (const float*)d_in[9];
    const float* bv = (const float*)d_in[10];
    const float* wo = (const float*)d_in[11];
    const float* bo = (const float*)d_in[12];
    const float* ln2w = (const float*)d_in[13];
    const float* ln2b = (const float*)d_in[14];
    const float* w1 = (const float*)d_in[15];
    const float* b1 = (const float*)d_in[16];
    const float* w2 = (const float*)d_in[17];
    const float* b2 = (const float*)d_in[18];
    const float* lnfw = (const float*)d_in[19];
    const float* lnfb = (const float*)d_in[20];
    const float* headw = (const float*)d_in[21];

    char* p = (char*)d_ws;
    auto alloc = [&](size_t bytes) {
        char* r = p;
        p += (bytes + 255) & ~(size_t)255;
        return r;
    };
    const long DD = (long)D * D, FD = (long)F * D;
    u16* qkvw_b = (u16*)alloc(L * 3 * DD * 2);   // [L][2304][768] fused
    u16* wo_b = (u16*)alloc(L * DD * 2);
    u16* w1_b = (u16*)alloc(L * FD * 2);
    u16* w2_b = (u16*)alloc(L * FD * 2);
    u16* hw_b = (u16*)alloc((long)V * D * 2);
    float* qkvbias = (float*)alloc(L * 2304 * 4);
    float* h = (float*)alloc((long)M * D * 4);
    u16* a = (u16*)alloc((long)M * D * 2);
    u16* qkvb = (u16*)alloc((long)M * 2304 * 2);
    u16* vT = (u16*)alloc(24L * 64 * T * 2);     // [B*H][64][T]
    u16* ctxb = (u16*)alloc((long)M * D * 2);
    u16* f1 = (u16*)alloc((long)M * F * 2);
    u16* sc = (u16*)alloc(24L * T * T * 2);

    auto cvt = [&](const float* src, u16* dst, long n, long chunk, long stride) {
        long blocks = (n + 1023) / 1024;
        if (blocks > 8192) blocks = 8192;
        cvt_kernel<<<dim3((unsigned)blocks), 256, 0, stream>>>(src, dst, n, chunk, stride);
    };
    cvt(wq, qkvw_b, L * DD, DD, 3 * DD);
    cvt(wk, qkvw_b + DD, L * DD, DD, 3 * DD);
    cvt(wv, qkvw_b + 2 * DD, L * DD, DD, 3 * DD);
    cvt(wo, wo_b, L * DD, L * DD, L * DD);
    cvt(w1, w1_b, L * FD, L * FD, L * FD);
    cvt(w2, w2_b, L * FD, L * FD, L * FD);
    cvt(headw, hw_b, (long)V * D, (long)V * D, (long)V * D);
    bias_fuse_kernel<<<dim3(18), 256, 0, stream>>>(bq, bk, bv, qkvbias);

    embed_kernel<<<dim3(M), 256, 0, stream>>>(x, tok, pos, h);

    const long sTD24 = (long)T * 2304;  // per-batch stride in fused qkv acts
    const long sTT = (long)T * T;       // per-head stride in scores
    for (int i = 0; i < L; i++) {
        ln_kernel<<<dim3(M), 256, 0, stream>>>(h, ln1w + i * D, ln1b + i * D, a);
        // fused qkv = a @ qkvw^T + qkvbias ; v written transposed to vT
        gemm2_kernel<128, 128, 6, false, false><<<dim3(16 * 18, 1, 1), 256, 0, stream>>>(
            a, D, 0, 0, qkvw_b + i * 3 * DD, D, 0, 0, qkvb, 2304, 0, 0,
            qkvbias + i * 2304, D, 16, 1, 0.f, vT);
        // scores = scale * Q@K^T   [24 batches of T x T], K=64
        gemm2_kernel<128, 64, 4, true, false><<<dim3(8 * 16, 1, 24), 256, 0, stream>>>(
            qkvb, 2304, sTD24, 64, qkvb + 768, 2304, sTD24, 64,
            sc, T, (long)Hn * sTT, sTT, nullptr, 64, 8, Hn, 0.125f, nullptr);
        softmax_kernel<<<dim3(T, 24), 256, 0, stream>>>(sc);
        // ctx = P@V : B = vT [64][T] per (b,h); causal K-limit
        gemm2_kernel<128, 64, 0, false, true><<<dim3(8 * 1, 1, 24), 256, 0, stream>>>(
            sc, T, (long)Hn * sTT, sTT, vT, T, (long)Hn * 64 * T, 64L * T,
            ctxb, D, (long)T * D, 64, nullptr, T, 8, Hn, 0.f, nullptr);
        // h += ctx @ wo^T + bo
        gemm2_kernel<64, 128, 3, false, false><<<dim3(32 * 6, 1, 1), 256, 0, stream>>>(
            ctxb, D, 0, 0, wo_b + i * DD, D, 0, 0, h, D, 0, 0,
            bo + i * D, D, 32, 1, 0.f, nullptr);
        ln_kernel<<<dim3(M), 256, 0, stream>>>(h, ln2w + i * D, ln2b + i * D, a);
        // f1 = relu(a @ w1^T + b1)
        gemm2_kernel<128, 128, 2, false, false><<<dim3(16 * 24, 1, 1), 256, 0, stream>>>(
            a, D, 0, 0, w1_b + i * FD, D, 0, 0, f1, F, 0, 0,
            b1 + i * F, D, 16, 1, 0.f, nullptr);
        // h += f1 @ w2^T + b2
        gemm2_kernel<64, 128, 3, false, false><<<dim3(32 * 6, 1, 1), 256, 0, stream>>>(
            f1, F, 0, 0, w2_b + i * FD, F, 0, 0, h, D, 0, 0,
            b2 + i * D, F, 32, 1, 0.f, nullptr);
    }
    ln_kernel<<<dim3(M), 256, 0, stream>>>(h, lnfw, lnfb, a);
    // logits = a @ head_w^T  -> f32 d_out
    gemm2_kernel<128, 128, 5, false, false><<<dim3(16 * 250, 1, 1), 256, 0, stream>>>(
        a, D, 0, 0, hw_b, D, 0, 0, d_out, V, 0, 0, nullptr, D, 16, 1, 0.f, nullptr);
}

// Round 3
// 1479.436 us; speedup vs baseline: 1.0477x; 1.0252x over previous
//
#include <hip/hip_runtime.h>

typedef unsigned short u16;
typedef __bf16 bf16x8 __attribute__((ext_vector_type(8)));
typedef float f32x4 __attribute__((ext_vector_type(4)));
typedef float f32x4v __attribute__((ext_vector_type(4)));
typedef u16 u16x4 __attribute__((ext_vector_type(4)));

__device__ __forceinline__ float bf2f(u16 u) {
    unsigned x = ((unsigned)u) << 16;
    return __builtin_bit_cast(float, x);
}
__device__ __forceinline__ u16 f2bf(float f) {
    unsigned x = __builtin_bit_cast(unsigned, f);
    unsigned r = (x + 0x7FFFu + ((x >> 16) & 1u)) >> 16;
    return (u16)r;
}

// ---------------- f32 -> bf16 conversion (chunk-strided dest) ----------------
__global__ __launch_bounds__(256) void cvt_kernel(const float* __restrict__ in,
                                                  u16* __restrict__ out, long n,
                                                  long chunk, long stride) {
    for (long i = (long)blockIdx.x * 1024 + (long)threadIdx.x * 4; i < n;
         i += (long)gridDim.x * 1024) {
        f32x4v v = *(const f32x4v*)(in + i);
        u16x4 o;
        o.x = f2bf(v.x); o.y = f2bf(v.y); o.z = f2bf(v.z); o.w = f2bf(v.w);
        long c = i / chunk, rrem = i - c * chunk;
        *(u16x4*)(out + c * stride + rrem) = o;
    }
}

// ---------------- fused qkv bias ----------------
__global__ __launch_bounds__(256) void bias_fuse_kernel(const float* __restrict__ bq,
                                                        const float* __restrict__ bk,
                                                        const float* __restrict__ bv,
                                                        float* __restrict__ dst) {
    int i = blockIdx.x * 256 + threadIdx.x;
    if (i < 6 * 768) {
        int l = i / 768, j = i % 768;
        dst[l * 2304 + j] = bq[i];
        dst[l * 2304 + 768 + j] = bk[i];
        dst[l * 2304 + 1536 + j] = bv[i];
    }
}

// ---------------- embedding ----------------
__global__ __launch_bounds__(256) void embed_kernel(const int* __restrict__ x,
                                                    const float* __restrict__ tok,
                                                    const float* __restrict__ pos,
                                                    float* __restrict__ h) {
    int row = blockIdx.x;           // [0, 2048)
    int t = row & 1023;
    long id = x[row];
    const float* te = tok + id * 768L;
    const float* pe = pos + (long)t * 768L;
    float* o = h + (long)row * 768L;
    for (int d = threadIdx.x; d < 768; d += 256) o[d] = te[d] + pe[d];
}

// ---------------- layernorm (f32 in, bf16 out) ----------------
__global__ __launch_bounds__(256) void ln_kernel(const float* __restrict__ x,
                                                 const float* __restrict__ w,
                                                 const float* __restrict__ b,
                                                 u16* __restrict__ out) {
    __shared__ float red[4];
    int row = blockIdx.x;
    const float* xr = x + (long)row * 768L;
    int tid = threadIdx.x, lane = tid & 63, wid = tid >> 6;
    float v0 = xr[tid], v1 = xr[tid + 256], v2 = xr[tid + 512];
    float s = v0 + v1 + v2;
    for (int o = 32; o; o >>= 1) s += __shfl_xor(s, o);
    if (lane == 0) red[wid] = s;
    __syncthreads();
    float mean = (red[0] + red[1] + red[2] + red[3]) * (1.f / 768.f);
    __syncthreads();
    float d0 = v0 - mean, d1 = v1 - mean, d2 = v2 - mean;
    float q = d0 * d0 + d1 * d1 + d2 * d2;
    for (int o = 32; o; o >>= 1) q += __shfl_xor(q, o);
    if (lane == 0) red[wid] = q;
    __syncthreads();
    float var = (red[0] + red[1] + red[2] + red[3]) * (1.f / 768.f);
    float rstd = rsqrtf(var + 1e-5f);
    u16* orow = out + (long)row * 768L;
    orow[tid]       = f2bf(d0 * rstd * w[tid]       + b[tid]);
    orow[tid + 256] = f2bf(d1 * rstd * w[tid + 256] + b[tid + 256]);
    orow[tid + 512] = f2bf(d2 * rstd * w[tid + 512] + b[tid + 512]);
}

// ---------------- softmax over score rows (in-place, bf16) ----------------
__global__ __launch_bounds__(256) void softmax_kernel(u16* __restrict__ scores) {
    __shared__ float red[4];
    int t = blockIdx.x, z = blockIdx.y;
    u16* row = scores + ((long)z * 1024 + t) * 1024L;
    int tid = threadIdx.x, lane = tid & 63, wid = tid >> 6;
    float v[4];
    float mx = -1e30f;
#pragma unroll
    for (int j = 0; j < 4; j++) {
        int s = tid + 256 * j;
        v[j] = (s <= t) ? bf2f(row[s]) : -1e30f;
        mx = fmaxf(mx, v[j]);
    }
    for (int o = 32; o; o >>= 1) mx = fmaxf(mx, __shfl_xor(mx, o));
    if (lane == 0) red[wid] = mx;
    __syncthreads();
    mx = fmaxf(fmaxf(red[0], red[1]), fmaxf(red[2], red[3]));
    __syncthreads();
    float e[4], ssum = 0.f;
#pragma unroll
    for (int j = 0; j < 4; j++) {
        int s = tid + 256 * j;
        e[j] = (s <= t) ? __expf(v[j] - mx) : 0.f;
        ssum += e[j];
    }
    for (int o = 32; o; o >>= 1) ssum += __shfl_xor(ssum, o);
    if (lane == 0) red[wid] = ssum;
    __syncthreads();
    ssum = red[0] + red[1] + red[2] + red[3];
    float inv = 1.f / ssum;
#pragma unroll
    for (int j = 0; j < 4; j++) row[tid + 256 * j] = f2bf(e[j] * inv);
}

// ---------------- MFMA GEMM v3: double-buffered 2-phase + swizzled LDS ----
// C = A @ B^T. Flat 1D grid, M-major + bijective XCD swizzle.
// LDS swizzle (rule #21, both-sides): linear global_load_lds dest; the SOURCE
// k-slice is permuted s^=(row>>1)&3 and the ds_read applies the same XOR.
// Quarter-wave then hits 8 distinct 4-bank windows, 2 rows each (2-way=free).
// EPI: 0 bf16; 1 +bias bf16; 2 relu(+bias) bf16; 3 C += acc+bias (f32);
//      4 *scale bf16; 5 f32; 6 qkv-split (q,k -> C, v -> aux transposed).
template <int BM, int BN, int EPI, bool CSKIP, bool KLIM>
__global__ __launch_bounds__(256) void gemm3_kernel(
    const u16* __restrict__ A, int lda, long sAb, long sAh,
    const u16* __restrict__ Bm, int ldb, long sBb, long sBh,
    void* __restrict__ Cv, int ldc, long sCb, long sCh,
    const float* __restrict__ bias, int K, int gm, int Hh, float scale,
    u16* __restrict__ aux) {
    constexpr int BK = 32;
    int nwg = gridDim.x, flat = blockIdx.x;
    int qq = nwg >> 3, rr = nwg & 7;
    int xcd = flat & 7, wi = flat >> 3;
    int swz = (xcd < rr) ? (xcd * (qq + 1) + wi) : (rr * (qq + 1) + (xcd - rr) * qq + wi);
    int ntile = swz / gm, mt = swz - ntile * gm;
    int bm0 = mt * BM, bn0 = ntile * BN;
    if (CSKIP && bn0 > bm0 + BM - 1) return;  // fully-masked causal tile
    int z = blockIdx.z;
    int zb = z / Hh, zh = z - zb * Hh;
    const u16* Ab = A + zb * sAb + zh * sAh + (long)bm0 * lda;
    const u16* Bb = Bm + zb * sBb + zh * sBh + (long)bn0 * ldb;

    __shared__ u16 As[2][BM * BK];
    __shared__ u16 Bs[2][BN * BK];

    int tid = threadIdx.x, lane = tid & 63, wid = tid >> 6;
    constexpr int WM = BM / 2, WN = BN / 2, MR = WM / 16, NR = WN / 16;
    int wm0 = (wid >> 1) * WM, wn0 = (wid & 1) * WN;

    f32x4 acc[MR][NR];
#pragma unroll
    for (int mi = 0; mi < MR; mi++)
#pragma unroll
        for (int ni = 0; ni < NR; ni++) acc[mi][ni] = 0.f;

    int Keff = KLIM ? (bm0 + BM < K ? bm0 + BM : K) : K;
    int nt = Keff / BK;

    // stage one K-tile into buffer `buf` (linear LDS dest, swizzled source)
    auto stage = [&](int buf, int k0) {
        constexpr int CA = BM * 4;  // 16B chunks of A
#pragma unroll
        for (int c0 = 0; c0 < CA; c0 += 256) {
            int c = c0 + tid;
            int row = c >> 2, sl = c & 3;
            int ks = sl ^ ((row >> 1) & 3);
            __builtin_amdgcn_global_load_lds(
                (const __attribute__((address_space(1))) unsigned*)(Ab + (long)row * lda + k0 + ks * 8),
                (__attribute__((address_space(3))) unsigned*)(As[buf] + c * 8), 16, 0, 0);
        }
        constexpr int CB = BN * 4;  // 16B chunks of B
#pragma unroll
        for (int c0 = 0; c0 < CB; c0 += 256) {
            int c = c0 + tid;
            int row = c >> 2, sl = c & 3;
            int ks = sl ^ ((row >> 1) & 3);
            __builtin_amdgcn_global_load_lds(
                (const __attribute__((address_space(1))) unsigned*)(Bb + (long)row * ldb + k0 + ks * 8),
                (__attribute__((address_space(3))) unsigned*)(Bs[buf] + c * 8), 16, 0, 0);
        }
    };

    stage(0, 0);
    __syncthreads();   // compiler emits vmcnt(0) drain here
    int cur = 0;
    int rA = lane & 15, sA = lane >> 4;
    int sswz = (sA ^ ((rA >> 1) & 3)) * 8;  // swizzled 16B slice offset (elements)
    for (int t = 0; t < nt; ++t) {
        if (t + 1 < nt) stage(cur ^ 1, (t + 1) * BK);  // prefetch next tile
        bf16x8 af[MR], bfr[NR];
#pragma unroll
        for (int mi = 0; mi < MR; mi++)
            af[mi] = *(const bf16x8*)(As[cur] + (wm0 + mi * 16 + rA) * BK + sswz);
#pragma unroll
        for (int ni = 0; ni < NR; ni++)
            bfr[ni] = *(const bf16x8*)(Bs[cur] + (wn0 + ni * 16 + rA) * BK + sswz);
#pragma unroll
        for (int mi = 0; mi < MR; mi++)
#pragma unroll
            for (int ni = 0; ni < NR; ni++)
                acc[mi][ni] = __builtin_amdgcn_mfma_f32_16x16x32_bf16(
                    af[mi], bfr[ni], acc[mi][ni], 0, 0, 0);
        __syncthreads();  // drains prefetch vmcnt + protects re-stage
        cur ^= 1;
    }

    long coff = zb * sCb + zh * sCh;
#pragma unroll
    for (int mi = 0; mi < MR; mi++)
#pragma unroll
        for (int ni = 0; ni < NR; ni++) {
            int gmb = bm0 + wm0 + mi * 16 + ((lane >> 4) << 2);
            int gn = bn0 + wn0 + ni * 16 + (lane & 15);
            if (EPI == 6) {
                if (gn < 1536) {
#pragma unroll
                    for (int j = 0; j < 4; j++)
                        ((u16*)Cv)[(long)(gmb + j) * ldc + gn] =
                            f2bf(acc[mi][ni][j] + bias[gn]);
                } else {
                    u16x4 o;
#pragma unroll
                    for (int j = 0; j < 4; j++) o[j] = f2bf(acc[mi][ni][j] + bias[gn]);
                    int hh = (gn - 1536) >> 6, dk = gn & 63;
                    long off = ((long)((gmb >> 10) * 12 + hh) * 64 + dk) * 1024 + (gmb & 1023);
                    *(u16x4*)(aux + off) = o;
                }
            } else {
#pragma unroll
                for (int j = 0; j < 4; j++) {
                    float v = acc[mi][ni][j];
                    long idx = coff + (long)(gmb + j) * ldc + gn;
                    if (EPI == 0) ((u16*)Cv)[idx] = f2bf(v);
                    else if (EPI == 1) ((u16*)Cv)[idx] = f2bf(v + bias[gn]);
                    else if (EPI == 2) ((u16*)Cv)[idx] = f2bf(fmaxf(v + bias[gn], 0.f));
                    else if (EPI == 3) { float* C = (float*)Cv; C[idx] = C[idx] + v + bias[gn]; }
                    else if (EPI == 4) ((u16*)Cv)[idx] = f2bf(v * scale);
                    else ((float*)Cv)[idx] = v;
                }
            }
        }
}

// ---------------- host side ----------------
extern "C" void kernel_launch(void* const* d_in, const int* in_sizes, int n_in,
                              void* d_out, int out_size, void* d_ws, size_t ws_size,
                              hipStream_t stream) {
    const int L = 6, D = 768, Hn = 12, F = 3072, T = 1024, V = 32000;
    const int M = 2048;  // B*T
    const int* x = (const int*)d_in[0];
    const float* tok = (const float*)d_in[1];
    const float* pos = (const float*)d_in[2];
    const float* ln1w = (const float*)d_in[3];
    const float* ln1b = (const float*)d_in[4];
    const float* wq = (const float*)d_in[5];
    const float* bq = (const float*)d_in[6];
    const float* wk = (const float*)d_in[7];
    const float* bk = (const float*)d_in[8];
    const float* wv = (const float*)d_in[9];
    const float* bv = (const float*)d_in[10];
    const float* wo = (const float*)d_in[11];
    const float* bo = (const float*)d_in[12];
    const float* ln2w = (const float*)d_in[13];
    const float* ln2b = (const float*)d_in[14];
    const float* w1 = (const float*)d_in[15];
    const float* b1 = (const float*)d_in[16];
    const float* w2 = (const float*)d_in[17];
    const float* b2 = (const float*)d_in[18];
    const float* lnfw = (const float*)d_in[19];
    const float* lnfb = (const float*)d_in[20];
    const float* headw = (const float*)d_in[21];

    char* p = (char*)d_ws;
    auto alloc = [&](size_t bytes) {
        char* r = p;
        p += (bytes + 255) & ~(size_t)255;
        return r;
    };
    const long DD = (long)D * D, FD = (long)F * D;
    u16* qkvw_b = (u16*)alloc(L * 3 * DD * 2);   // [L][2304][768] fused
    u16* wo_b = (u16*)alloc(L * DD * 2);
    u16* w1_b = (u16*)alloc(L * FD * 2);
    u16* w2_b = (u16*)alloc(L * FD * 2);
    u16* hw_b = (u16*)alloc((long)V * D * 2);
    float* qkvbias = (float*)alloc(L * 2304 * 4);
    float* h = (float*)alloc((long)M * D * 4);
    u16* a = (u16*)alloc((long)M * D * 2);
    u16* qkvb = (u16*)alloc((long)M * 2304 * 2);
    u16* vT = (u16*)alloc(24L * 64 * T * 2);     // [B*H][64][T]
    u16* ctxb = (u16*)alloc((long)M * D * 2);
    u16* f1 = (u16*)alloc((long)M * F * 2);
    u16* sc = (u16*)alloc(24L * T * T * 2);

    auto cvt = [&](const float* src, u16* dst, long n, long chunk, long stride) {
        long blocks = (n + 1023) / 1024;
        if (blocks > 8192) blocks = 8192;
        cvt_kernel<<<dim3((unsigned)blocks), 256, 0, stream>>>(src, dst, n, chunk, stride);
    };
    cvt(wq, qkvw_b, L * DD, DD, 3 * DD);
    cvt(wk, qkvw_b + DD, L * DD, DD, 3 * DD);
    cvt(wv, qkvw_b + 2 * DD, L * DD, DD, 3 * DD);
    cvt(wo, wo_b, L * DD, L * DD, L * DD);
    cvt(w1, w1_b, L * FD, L * FD, L * FD);
    cvt(w2, w2_b, L * FD, L * FD, L * FD);
    cvt(headw, hw_b, (long)V * D, (long)V * D, (long)V * D);
    bias_fuse_kernel<<<dim3(18), 256, 0, stream>>>(bq, bk, bv, qkvbias);

    embed_kernel<<<dim3(M), 256, 0, stream>>>(x, tok, pos, h);

    const long sTD24 = (long)T * 2304;  // per-batch stride in fused qkv acts
    const long sTT = (long)T * T;       // per-head stride in scores
    for (int i = 0; i < L; i++) {
        ln_kernel<<<dim3(M), 256, 0, stream>>>(h, ln1w + i * D, ln1b + i * D, a);
        // fused qkv = a @ qkvw^T + qkvbias ; v written transposed to vT
        gemm3_kernel<128, 128, 6, false, false><<<dim3(16 * 18, 1, 1), 256, 0, stream>>>(
            a, D, 0, 0, qkvw_b + i * 3 * DD, D, 0, 0, qkvb, 2304, 0, 0,
            qkvbias + i * 2304, D, 16, 1, 0.f, vT);
        // scores = scale * Q@K^T   [24 batches of T x T], K=64
        gemm3_kernel<128, 64, 4, true, false><<<dim3(8 * 16, 1, 24), 256, 0, stream>>>(
            qkvb, 2304, sTD24, 64, qkvb + 768, 2304, sTD24, 64,
            sc, T, (long)Hn * sTT, sTT, nullptr, 64, 8, Hn, 0.125f, nullptr);
        softmax_kernel<<<dim3(T, 24), 256, 0, stream>>>(sc);
        // ctx = P@V : B = vT [64][T] per (b,h); causal K-limit
        gemm3_kernel<128, 64, 0, false, true><<<dim3(8 * 1, 1, 24), 256, 0, stream>>>(
            sc, T, (long)Hn * sTT, sTT, vT, T, (long)Hn * 64 * T, 64L * T,
            ctxb, D, (long)T * D, 64, nullptr, T, 8, Hn, 0.f, nullptr);
        // h += ctx @ wo^T + bo
        gemm3_kernel<64, 128, 3, false, false><<<dim3(32 * 6, 1, 1), 256, 0, stream>>>(
            ctxb, D, 0, 0, wo_b + i * DD, D, 0, 0, h, D, 0, 0,
            bo + i * D, D, 32, 1, 0.f, nullptr);
        ln_kernel<<<dim3(M), 256, 0, stream>>>(h, ln2w + i * D, ln2b + i * D, a);
        // f1 = relu(a @ w1^T + b1)
        gemm3_kernel<128, 128, 2, false, false><<<dim3(16 * 24, 1, 1), 256, 0, stream>>>(
            a, D, 0, 0, w1_b + i * FD, D, 0, 0, f1, F, 0, 0,
            b1 + i * F, D, 16, 1, 0.f, nullptr);
        // h += f1 @ w2^T + b2
        gemm3_kernel<64, 128, 3, false, false><<<dim3(32 * 6, 1, 1), 256, 0, stream>>>(
            f1, F, 0, 0, w2_b + i * FD, F, 0, 0, h, D, 0, 0,
            b2 + i * D, F, 32, 1, 0.f, nullptr);
    }
    ln_kernel<<<dim3(M), 256, 0, stream>>>(h, lnfw, lnfb, a);
    // logits = a @ head_w^T  -> f32 d_out
    gemm3_kernel<128, 128, 5, false, false><<<dim3(16 * 250, 1, 1), 256, 0, stream>>>(
        a, D, 0, 0, hw_b, D, 0, 0, d_out, V, 0, 0, nullptr, D, 16, 1, 0.f, nullptr);
}

// Round 4
// 1331.173 us; speedup vs baseline: 1.1644x; 1.1114x over previous
//
#include <hip/hip_runtime.h>

typedef unsigned short u16;
typedef __bf16 bf16x8 __attribute__((ext_vector_type(8)));
typedef float f32x4 __attribute__((ext_vector_type(4)));
typedef float f32x4v __attribute__((ext_vector_type(4)));
typedef u16 u16x4 __attribute__((ext_vector_type(4)));

__device__ __forceinline__ float bf2f(u16 u) {
    unsigned x = ((unsigned)u) << 16;
    return __builtin_bit_cast(float, x);
}
__device__ __forceinline__ u16 f2bf(float f) {
    unsigned x = __builtin_bit_cast(unsigned, f);
    unsigned r = (x + 0x7FFFu + ((x >> 16) & 1u)) >> 16;
    return (u16)r;
}

// ---------------- f32 -> bf16 conversion (chunk-strided dest) ----------------
__global__ __launch_bounds__(256) void cvt_kernel(const float* __restrict__ in,
                                                  u16* __restrict__ out, long n,
                                                  long chunk, long stride) {
    for (long i = (long)blockIdx.x * 1024 + (long)threadIdx.x * 4; i < n;
         i += (long)gridDim.x * 1024) {
        f32x4v v = *(const f32x4v*)(in + i);
        u16x4 o;
        o.x = f2bf(v.x); o.y = f2bf(v.y); o.z = f2bf(v.z); o.w = f2bf(v.w);
        long c = i / chunk, rrem = i - c * chunk;
        *(u16x4*)(out + c * stride + rrem) = o;
    }
}

// ---------------- fused qkv bias ----------------
__global__ __launch_bounds__(256) void bias_fuse_kernel(const float* __restrict__ bq,
                                                        const float* __restrict__ bk,
                                                        const float* __restrict__ bv,
                                                        float* __restrict__ dst) {
    int i = blockIdx.x * 256 + threadIdx.x;
    if (i < 6 * 768) {
        int l = i / 768, j = i % 768;
        dst[l * 2304 + j] = bq[i];
        dst[l * 2304 + 768 + j] = bk[i];
        dst[l * 2304 + 1536 + j] = bv[i];
    }
}

// ---------------- embedding ----------------
__global__ __launch_bounds__(256) void embed_kernel(const int* __restrict__ x,
                                                    const float* __restrict__ tok,
                                                    const float* __restrict__ pos,
                                                    float* __restrict__ h) {
    int row = blockIdx.x;           // [0, 2048)
    int t = row & 1023;
    long id = x[row];
    const float* te = tok + id * 768L;
    const float* pe = pos + (long)t * 768L;
    float* o = h + (long)row * 768L;
    for (int d = threadIdx.x; d < 768; d += 256) o[d] = te[d] + pe[d];
}

// ---------------- layernorm (f32 in, bf16 out) ----------------
__global__ __launch_bounds__(256) void ln_kernel(const float* __restrict__ x,
                                                 const float* __restrict__ w,
                                                 const float* __restrict__ b,
                                                 u16* __restrict__ out) {
    __shared__ float red[4];
    int row = blockIdx.x;
    const float* xr = x + (long)row * 768L;
    int tid = threadIdx.x, lane = tid & 63, wid = tid >> 6;
    float v0 = xr[tid], v1 = xr[tid + 256], v2 = xr[tid + 512];
    float s = v0 + v1 + v2;
    for (int o = 32; o; o >>= 1) s += __shfl_xor(s, o);
    if (lane == 0) red[wid] = s;
    __syncthreads();
    float mean = (red[0] + red[1] + red[2] + red[3]) * (1.f / 768.f);
    __syncthreads();
    float d0 = v0 - mean, d1 = v1 - mean, d2 = v2 - mean;
    float q = d0 * d0 + d1 * d1 + d2 * d2;
    for (int o = 32; o; o >>= 1) q += __shfl_xor(q, o);
    if (lane == 0) red[wid] = q;
    __syncthreads();
    float var = (red[0] + red[1] + red[2] + red[3]) * (1.f / 768.f);
    float rstd = rsqrtf(var + 1e-5f);
    u16* orow = out + (long)row * 768L;
    orow[tid]       = f2bf(d0 * rstd * w[tid]       + b[tid]);
    orow[tid + 256] = f2bf(d1 * rstd * w[tid + 256] + b[tid + 256]);
    orow[tid + 512] = f2bf(d2 * rstd * w[tid + 512] + b[tid + 512]);
}

// ---------------- flash attention (causal, DK=64) ----------------
// Grid: (16 q-tiles, 1, 24 b*h). 4 waves x 16 q-rows = QBLK 64, KVBLK 64.
// K tile [64 tok][64 dk] and V^T tile [64 dk][64 tok] staged in LDS with the
// both-sides chunk swizzle (chunk ^= (row>>1)&3 within each 32-elem half).
// Online softmax per q-row via quarter-wave shuffle reductions (all 64 lanes
// active). P -> per-wave LDS (swizzled) -> PV MFMA accumulate in f32.
__global__ __launch_bounds__(256) void flash_kernel(
    const u16* __restrict__ qkv,   // [2048][2304]; q col 0, k col 768
    const u16* __restrict__ vT,    // [24][64][1024]
    u16* __restrict__ ctx) {       // [2048][768]
    int z = blockIdx.z;
    int zb = z / 12, zh = z - zb * 12;
    int qt = (int)gridDim.x - 1 - (int)blockIdx.x;  // big tiles first
    int q0 = qt * 64;
    int tid = threadIdx.x, lane = tid & 63, wid = tid >> 6;
    int rA = lane & 15, sA = lane >> 4;

    const u16* Qbase = qkv + (long)zb * 1024 * 2304 + zh * 64;
    const u16* Kbase = Qbase + 768;
    const u16* Vbase = vT + (long)z * 64 * 1024;

    __shared__ u16 Ks[64 * 64];
    __shared__ u16 Vs[64 * 64];
    __shared__ u16 Ps[4][16 * 64];

    // Q fragments (held in registers): row = q0 + wid*16 + rA, k = h*32+sA*8+e
    bf16x8 aq[2];
    {
        const u16* qrow = Qbase + (long)(q0 + wid * 16 + rA) * 2304;
        aq[0] = *(const bf16x8*)(qrow + sA * 8);
        aq[1] = *(const bf16x8*)(qrow + 32 + sA * 8);
    }

    float m[4], l[4];
    f32x4 acc_o[4];
#pragma unroll
    for (int j = 0; j < 4; j++) { m[j] = -1e30f; l[j] = 0.f; }
#pragma unroll
    for (int nf = 0; nf < 4; nf++) acc_o[nf] = 0.f;

    int grow0 = q0 + wid * 16 + sA * 4;  // this lane's first q-row
    int nkv = qt + 1;
    for (int t = 0; t < nkv; ++t) {
        int kv0 = t * 64;
        // stage K tile: row = token, 64 dk elems = 2 halves x 4 chunks x 8
#pragma unroll
        for (int c0 = 0; c0 < 512; c0 += 256) {
            int c = c0 + tid;
            int row = c >> 3, half = (c >> 2) & 1, sl = c & 3;
            int ks = sl ^ ((row >> 1) & 3);
            __builtin_amdgcn_global_load_lds(
                (const __attribute__((address_space(1))) unsigned*)(Kbase + (long)(kv0 + row) * 2304 + half * 32 + ks * 8),
                (__attribute__((address_space(3))) unsigned*)(Ks + c * 8), 16, 0, 0);
        }
        // stage V^T tile: row = dk, cols = tokens kv0..kv0+63
#pragma unroll
        for (int c0 = 0; c0 < 512; c0 += 256) {
            int c = c0 + tid;
            int row = c >> 3, half = (c >> 2) & 1, sl = c & 3;
            int ks = sl ^ ((row >> 1) & 3);
            __builtin_amdgcn_global_load_lds(
                (const __attribute__((address_space(1))) unsigned*)(Vbase + (long)row * 1024 + kv0 + half * 32 + ks * 8),
                (__attribute__((address_space(3))) unsigned*)(Vs + c * 8), 16, 0, 0);
        }
        __syncthreads();

        // QK^T: s[nf] over 4 col-fragments, 2 k-steps of 32 dk
        f32x4 s[4];
#pragma unroll
        for (int nf = 0; nf < 4; nf++) s[nf] = 0.f;
#pragma unroll
        for (int h = 0; h < 2; h++)
#pragma unroll
            for (int nf = 0; nf < 4; nf++) {
                int row = nf * 16 + rA;
                bf16x8 bk_ = *(const bf16x8*)(Ks + row * 64 + h * 32 + ((sA ^ ((row >> 1) & 3))) * 8);
                s[nf] = __builtin_amdgcn_mfma_f32_16x16x32_bf16(aq[h], bk_, s[nf], 0, 0, 0);
            }
        // scale + causal mask
#pragma unroll
        for (int nf = 0; nf < 4; nf++) {
            int col = kv0 + nf * 16 + rA;
#pragma unroll
            for (int j = 0; j < 4; j++)
                s[nf][j] = (col <= grow0 + j) ? s[nf][j] * 0.125f : -1e30f;
        }
        // per-row tile max (quarter-wave reduce)
        float pm[4];
#pragma unroll
        for (int j = 0; j < 4; j++) {
            float v = fmaxf(fmaxf(s[0][j], s[1][j]), fmaxf(s[2][j], s[3][j]));
#pragma unroll
            for (int o = 1; o < 16; o <<= 1) v = fmaxf(v, __shfl_xor(v, o));
            pm[j] = v;
        }
        float esc[4];
#pragma unroll
        for (int j = 0; j < 4; j++) {
            float mn = fmaxf(m[j], pm[j]);
            esc[j] = __expf(m[j] - mn);
            m[j] = mn;
        }
        // P = exp(s - m), write to per-wave LDS (swizzled), accumulate row sums
        float ts[4] = {0.f, 0.f, 0.f, 0.f};
#pragma unroll
        for (int nf = 0; nf < 4; nf++) {
            int c = nf * 16 + rA;
            int half = c >> 5, ch = (c >> 3) & 3, e = c & 7;
#pragma unroll
            for (int j = 0; j < 4; j++) {
                float p = __expf(s[nf][j] - m[j]);
                ts[j] += p;
                int r = sA * 4 + j;
                Ps[wid][r * 64 + half * 32 + (ch ^ ((r >> 1) & 3)) * 8 + e] = f2bf(p);
            }
        }
#pragma unroll
        for (int j = 0; j < 4; j++) {
            float v = ts[j];
#pragma unroll
            for (int o = 1; o < 16; o <<= 1) v += __shfl_xor(v, o);
            l[j] = l[j] * esc[j] + v;
        }
#pragma unroll
        for (int nf = 0; nf < 4; nf++)
#pragma unroll
            for (int j = 0; j < 4; j++) acc_o[nf][j] *= esc[j];

        // PV: A = P (per-wave LDS), B = V^T tile; accumulate into acc_o
#pragma unroll
        for (int h = 0; h < 2; h++) {
            bf16x8 ap = *(const bf16x8*)(Ps[wid] + rA * 64 + h * 32 + ((sA ^ ((rA >> 1) & 3))) * 8);
#pragma unroll
            for (int nf = 0; nf < 4; nf++) {
                int row = nf * 16 + rA;
                bf16x8 bv_ = *(const bf16x8*)(Vs + row * 64 + h * 32 + ((sA ^ ((row >> 1) & 3))) * 8);
                acc_o[nf] = __builtin_amdgcn_mfma_f32_16x16x32_bf16(ap, bv_, acc_o[nf], 0, 0, 0);
            }
        }
        __syncthreads();  // protect Ks/Vs before next stage
    }

    // epilogue: ctx[row][zh*64 + dk] = acc_o / l
    float inv[4];
#pragma unroll
    for (int j = 0; j < 4; j++) inv[j] = 1.f / l[j];
    u16* crow = ctx + ((long)zb * 1024 + q0 + wid * 16) * 768 + zh * 64;
#pragma unroll
    for (int nf = 0; nf < 4; nf++)
#pragma unroll
        for (int j = 0; j < 4; j++)
            crow[(long)(sA * 4 + j) * 768 + nf * 16 + rA] = f2bf(acc_o[nf][j] * inv[j]);
}

// ---------------- MFMA GEMM v3: double-buffered 2-phase + swizzled LDS ----
// C = A @ B^T. Flat 1D grid, M-major + bijective XCD swizzle.
// EPI: 1 +bias bf16; 2 relu(+bias) bf16; 3 C += acc+bias (f32);
//      5 f32; 6 qkv-split (q,k -> C, v -> aux transposed).
template <int BM, int BN, int EPI, bool CSKIP, bool KLIM>
__global__ __launch_bounds__(256) void gemm3_kernel(
    const u16* __restrict__ A, int lda, long sAb, long sAh,
    const u16* __restrict__ Bm, int ldb, long sBb, long sBh,
    void* __restrict__ Cv, int ldc, long sCb, long sCh,
    const float* __restrict__ bias, int K, int gm, int Hh, float scale,
    u16* __restrict__ aux) {
    constexpr int BK = 32;
    int nwg = gridDim.x, flat = blockIdx.x;
    int qq = nwg >> 3, rr = nwg & 7;
    int xcd = flat & 7, wi = flat >> 3;
    int swz = (xcd < rr) ? (xcd * (qq + 1) + wi) : (rr * (qq + 1) + (xcd - rr) * qq + wi);
    int ntile = swz / gm, mt = swz - ntile * gm;
    int bm0 = mt * BM, bn0 = ntile * BN;
    if (CSKIP && bn0 > bm0 + BM - 1) return;
    int z = blockIdx.z;
    int zb = z / Hh, zh = z - zb * Hh;
    const u16* Ab = A + zb * sAb + zh * sAh + (long)bm0 * lda;
    const u16* Bb = Bm + zb * sBb + zh * sBh + (long)bn0 * ldb;

    __shared__ u16 As[2][BM * BK];
    __shared__ u16 Bs[2][BN * BK];

    int tid = threadIdx.x, lane = tid & 63, wid = tid >> 6;
    constexpr int WM = BM / 2, WN = BN / 2, MR = WM / 16, NR = WN / 16;
    int wm0 = (wid >> 1) * WM, wn0 = (wid & 1) * WN;

    f32x4 acc[MR][NR];
#pragma unroll
    for (int mi = 0; mi < MR; mi++)
#pragma unroll
        for (int ni = 0; ni < NR; ni++) acc[mi][ni] = 0.f;

    int Keff = KLIM ? (bm0 + BM < K ? bm0 + BM : K) : K;
    int nt = Keff / BK;

    auto stage = [&](int buf, int k0) {
        constexpr int CA = BM * 4;
#pragma unroll
        for (int c0 = 0; c0 < CA; c0 += 256) {
            int c = c0 + tid;
            int row = c >> 2, sl = c & 3;
            int ks = sl ^ ((row >> 1) & 3);
            __builtin_amdgcn_global_load_lds(
                (const __attribute__((address_space(1))) unsigned*)(Ab + (long)row * lda + k0 + ks * 8),
                (__attribute__((address_space(3))) unsigned*)(As[buf] + c * 8), 16, 0, 0);
        }
        constexpr int CB = BN * 4;
#pragma unroll
        for (int c0 = 0; c0 < CB; c0 += 256) {
            int c = c0 + tid;
            int row = c >> 2, sl = c & 3;
            int ks = sl ^ ((row >> 1) & 3);
            __builtin_amdgcn_global_load_lds(
                (const __attribute__((address_space(1))) unsigned*)(Bb + (long)row * ldb + k0 + ks * 8),
                (__attribute__((address_space(3))) unsigned*)(Bs[buf] + c * 8), 16, 0, 0);
        }
    };

    stage(0, 0);
    __syncthreads();
    int cur = 0;
    int rA = lane & 15, sA = lane >> 4;
    int sswz = (sA ^ ((rA >> 1) & 3)) * 8;
    for (int t = 0; t < nt; ++t) {
        if (t + 1 < nt) stage(cur ^ 1, (t + 1) * BK);
        bf16x8 af[MR], bfr[NR];
#pragma unroll
        for (int mi = 0; mi < MR; mi++)
            af[mi] = *(const bf16x8*)(As[cur] + (wm0 + mi * 16 + rA) * BK + sswz);
#pragma unroll
        for (int ni = 0; ni < NR; ni++)
            bfr[ni] = *(const bf16x8*)(Bs[cur] + (wn0 + ni * 16 + rA) * BK + sswz);
#pragma unroll
        for (int mi = 0; mi < MR; mi++)
#pragma unroll
            for (int ni = 0; ni < NR; ni++)
                acc[mi][ni] = __builtin_amdgcn_mfma_f32_16x16x32_bf16(
                    af[mi], bfr[ni], acc[mi][ni], 0, 0, 0);
        __syncthreads();
        cur ^= 1;
    }

    long coff = zb * sCb + zh * sCh;
#pragma unroll
    for (int mi = 0; mi < MR; mi++)
#pragma unroll
        for (int ni = 0; ni < NR; ni++) {
            int gmb = bm0 + wm0 + mi * 16 + ((lane >> 4) << 2);
            int gn = bn0 + wn0 + ni * 16 + (lane & 15);
            if (EPI == 6) {
                if (gn < 1536) {
#pragma unroll
                    for (int j = 0; j < 4; j++)
                        ((u16*)Cv)[(long)(gmb + j) * ldc + gn] =
                            f2bf(acc[mi][ni][j] + bias[gn]);
                } else {
                    u16x4 o;
#pragma unroll
                    for (int j = 0; j < 4; j++) o[j] = f2bf(acc[mi][ni][j] + bias[gn]);
                    int hh = (gn - 1536) >> 6, dk = gn & 63;
                    long off = ((long)((gmb >> 10) * 12 + hh) * 64 + dk) * 1024 + (gmb & 1023);
                    *(u16x4*)(aux + off) = o;
                }
            } else {
#pragma unroll
                for (int j = 0; j < 4; j++) {
                    float v = acc[mi][ni][j];
                    long idx = coff + (long)(gmb + j) * ldc + gn;
                    if (EPI == 1) ((u16*)Cv)[idx] = f2bf(v + bias[gn]);
                    else if (EPI == 2) ((u16*)Cv)[idx] = f2bf(fmaxf(v + bias[gn], 0.f));
                    else if (EPI == 3) { float* C = (float*)Cv; C[idx] = C[idx] + v + bias[gn]; }
                    else if (EPI == 5) ((float*)Cv)[idx] = v;
                    else ((u16*)Cv)[idx] = f2bf(v * scale);
                }
            }
        }
}

// ---------------- host side ----------------
extern "C" void kernel_launch(void* const* d_in, const int* in_sizes, int n_in,
                              void* d_out, int out_size, void* d_ws, size_t ws_size,
                              hipStream_t stream) {
    const int L = 6, D = 768, Hn = 12, F = 3072, T = 1024, V = 32000;
    const int M = 2048;  // B*T
    const int* x = (const int*)d_in[0];
    const float* tok = (const float*)d_in[1];
    const float* pos = (const float*)d_in[2];
    const float* ln1w = (const float*)d_in[3];
    const float* ln1b = (const float*)d_in[4];
    const float* wq = (const float*)d_in[5];
    const float* bq = (const float*)d_in[6];
    const float* wk = (const float*)d_in[7];
    const float* bk = (const float*)d_in[8];
    const float* wv = (const float*)d_in[9];
    const float* bv = (const float*)d_in[10];
    const float* wo = (const float*)d_in[11];
    const float* bo = (const float*)d_in[12];
    const float* ln2w = (const float*)d_in[13];
    const float* ln2b = (const float*)d_in[14];
    const float* w1 = (const float*)d_in[15];
    const float* b1 = (const float*)d_in[16];
    const float* w2 = (const float*)d_in[17];
    const float* b2 = (const float*)d_in[18];
    const float* lnfw = (const float*)d_in[19];
    const float* lnfb = (const float*)d_in[20];
    const float* headw = (const float*)d_in[21];

    char* p = (char*)d_ws;
    auto alloc = [&](size_t bytes) {
        char* r = p;
        p += (bytes + 255) & ~(size_t)255;
        return r;
    };
    const long DD = (long)D * D, FD = (long)F * D;
    u16* qkvw_b = (u16*)alloc(L * 3 * DD * 2);   // [L][2304][768] fused
    u16* wo_b = (u16*)alloc(L * DD * 2);
    u16* w1_b = (u16*)alloc(L * FD * 2);
    u16* w2_b = (u16*)alloc(L * FD * 2);
    u16* hw_b = (u16*)alloc((long)V * D * 2);
    float* qkvbias = (float*)alloc(L * 2304 * 4);
    float* h = (float*)alloc((long)M * D * 4);
    u16* a = (u16*)alloc((long)M * D * 2);
    u16* qkvb = (u16*)alloc((long)M * 2304 * 2);
    u16* vT = (u16*)alloc(24L * 64 * T * 2);     // [B*H][64][T]
    u16* ctxb = (u16*)alloc((long)M * D * 2);
    u16* f1 = (u16*)alloc((long)M * F * 2);

    auto cvt = [&](const float* src, u16* dst, long n, long chunk, long stride) {
        long blocks = (n + 1023) / 1024;
        if (blocks > 8192) blocks = 8192;
        cvt_kernel<<<dim3((unsigned)blocks), 256, 0, stream>>>(src, dst, n, chunk, stride);
    };
    cvt(wq, qkvw_b, L * DD, DD, 3 * DD);
    cvt(wk, qkvw_b + DD, L * DD, DD, 3 * DD);
    cvt(wv, qkvw_b + 2 * DD, L * DD, DD, 3 * DD);
    cvt(wo, wo_b, L * DD, L * DD, L * DD);
    cvt(w1, w1_b, L * FD, L * FD, L * FD);
    cvt(w2, w2_b, L * FD, L * FD, L * FD);
    cvt(headw, hw_b, (long)V * D, (long)V * D, (long)V * D);
    bias_fuse_kernel<<<dim3(18), 256, 0, stream>>>(bq, bk, bv, qkvbias);

    embed_kernel<<<dim3(M), 256, 0, stream>>>(x, tok, pos, h);

    for (int i = 0; i < L; i++) {
        ln_kernel<<<dim3(M), 256, 0, stream>>>(h, ln1w + i * D, ln1b + i * D, a);
        // fused qkv = a @ qkvw^T + qkvbias ; v written transposed to vT
        gemm3_kernel<128, 128, 6, false, false><<<dim3(16 * 18, 1, 1), 256, 0, stream>>>(
            a, D, 0, 0, qkvw_b + i * 3 * DD, D, 0, 0, qkvb, 2304, 0, 0,
            qkvbias + i * 2304, D, 16, 1, 0.f, vT);
        // fused causal flash attention -> ctxb
        flash_kernel<<<dim3(16, 1, 24), 256, 0, stream>>>(qkvb, vT, ctxb);
        // h += ctx @ wo^T + bo
        gemm3_kernel<64, 128, 3, false, false><<<dim3(32 * 6, 1, 1), 256, 0, stream>>>(
            ctxb, D, 0, 0, wo_b + i * DD, D, 0, 0, h, D, 0, 0,
            bo + i * D, D, 32, 1, 0.f, nullptr);
        ln_kernel<<<dim3(M), 256, 0, stream>>>(h, ln2w + i * D, ln2b + i * D, a);
        // f1 = relu(a @ w1^T + b1)
        gemm3_kernel<128, 128, 2, false, false><<<dim3(16 * 24, 1, 1), 256, 0, stream>>>(
            a, D, 0, 0, w1_b + i * FD, D, 0, 0, f1, F, 0, 0,
            b1 + i * F, D, 16, 1, 0.f, nullptr);
        // h += f1 @ w2^T + b2
        gemm3_kernel<64, 128, 3, false, false><<<dim3(32 * 6, 1, 1), 256, 0, stream>>>(
            f1, F, 0, 0, w2_b + i * FD, F, 0, 0, h, D, 0, 0,
            b2 + i * D, F, 32, 1, 0.f, nullptr);
    }
    ln_kernel<<<dim3(M), 256, 0, stream>>>(h, lnfw, lnfb, a);
    // logits = a @ head_w^T  -> f32 d_out
    gemm3_kernel<128, 128, 5, false, false><<<dim3(16 * 250, 1, 1), 256, 0, stream>>>(
        a, D, 0, 0, hw_b, D, 0, 0, d_out, V, 0, 0, nullptr, D, 16, 1, 0.f, nullptr);
}